// Round 12
// baseline (287.191 us; speedup 1.0000x reference)
//
#include <hip/hip_runtime.h>

#define NN 50000
#define EE 800000
#define DD 128
#define CC 64
#define LDA 264    // LDS A row stride in u16: 256 data + 8 pad (2-way bank alias = free)
#define EMAX 2048  // LDS edge-cache cap per 64-node block (mean 1024, sd 32 -> 32 sigma)

// bucketed CSR fill
#define BSH 7                                 // 128 dst-nodes per bucket
#define NBKT ((NN + (1 << BSH) - 1) >> BSH)   // 391
#define BCAP 3072                             // mean 2048, sd ~45 -> 22-sigma margin
#define EPB 4096                              // edges per bucket-block (1024 thr x 4)

typedef unsigned char u8;
typedef unsigned short u16;
typedef unsigned int u32;
typedef __attribute__((ext_vector_type(8))) short short8;   // 8 bf16
typedef __attribute__((ext_vector_type(4))) float f32x4;
typedef __attribute__((ext_vector_type(2))) float f32x2;

__device__ __forceinline__ float bf2f(u16 u) {
    union { u32 i; float f; } v; v.i = ((u32)u) << 16; return v.f;
}
__device__ __forceinline__ u16 f2bf(float f) {
    union { float f; u32 i; } v; v.f = f;
    u32 x = v.i;
    u32 r = x + 0x7fffu + ((x >> 16) & 1u);   // round-to-nearest-even
    return (u16)(r >> 16);
}

// ---------------- phase A: bucket edges by dst>>7, NO global per-edge atomics ----------------

__global__ __launch_bounds__(1024) void k_bucket(const int* __restrict__ src,
                                                 const int* __restrict__ dst,
                                                 int* __restrict__ bcnt,
                                                 u32* __restrict__ bkt) {
    __shared__ int cnt[NBKT];
    __shared__ int base[NBKT];
    int t = threadIdx.x;
    int e0 = blockIdx.x * EPB;
    for (int i = t; i < NBKT; i += 1024) cnt[i] = 0;
    __syncthreads();
    int bk[4], lp[4];
    u32 pk[4];
#pragma unroll
    for (int j = 0; j < 4; ++j) {
        int e = e0 + t + 1024 * j;
        if (e < EE) {
            int d = dst[e];
            int s = src[e];
            bk[j] = d >> BSH;
            pk[j] = (u32)s | ((u32)(d & 127) << 16);
            lp[j] = atomicAdd(&cnt[bk[j]], 1);
        } else {
            bk[j] = -1;
        }
    }
    __syncthreads();
    for (int i = t; i < NBKT; i += 1024)
        base[i] = atomicAdd(&bcnt[i], cnt[i]);
    __syncthreads();
#pragma unroll
    for (int j = 0; j < 4; ++j) {
        if (bk[j] >= 0)
            bkt[(size_t)bk[j] * BCAP + base[bk[j]] + lp[j]] = pk[j];
    }
}

// ---------------- phase B: one block per bucket: local histogram/scan -> row_off,
// inv_deg, csr (all contiguous single-block-owned writes) ----------------

__global__ __launch_bounds__(512) void k_fill2(const int* __restrict__ bcnt,
                                               const u32* __restrict__ bkt,
                                               int* __restrict__ row_off,
                                               float* __restrict__ inv_deg,
                                               int* __restrict__ csr) {
    __shared__ int cnt[128];
    __shared__ int off[128];
    __shared__ int wtot;
    int b = blockIdx.x;
    int t = threadIdx.x;
    int lane = t & 63;
    int n = bcnt[b];

    // exclusive prefix of bcnt[0..b) -- redundant per-wave reduce, L2-hot
    int part = 0;
    for (int i = lane; i < b; i += 64) part += bcnt[i];
#pragma unroll
    for (int o = 1; o < 64; o <<= 1) part += __shfl_xor(part, o);
    int gbase = part;   // same value in every wave

    if (t < 128) cnt[t] = 0;
    __syncthreads();

    const u32* bp = bkt + (size_t)b * BCAP;
    int dl[6], sv[6], lp[6];
#pragma unroll
    for (int j = 0; j < 6; ++j) {           // BCAP/512 = 6
        int i = t + 512 * j;
        if (i < n) {
            u32 pk = bp[i];
            dl[j] = (int)(pk >> 16) & 127;
            sv[j] = (int)(pk & 0xffffu);
            lp[j] = atomicAdd(&cnt[dl[j]], 1);
        } else {
            dl[j] = -1;
        }
    }
    __syncthreads();

    int x = 0, v = 0;
    if (t < 128) {
        v = cnt[t];
        x = v;
#pragma unroll
        for (int o = 1; o < 64; o <<= 1) {
            int y = __shfl_up(x, o, 64);
            if (lane >= o) x += y;
        }
        if (t == 63) wtot = x;
    }
    __syncthreads();
    if (t < 128) {
        int excl = x - v + ((t >= 64) ? wtot : 0);
        off[t] = excl;
        int node = (b << BSH) + t;
        if (node < NN) {
            row_off[node] = gbase + excl;
            inv_deg[node] = 1.0f / fmaxf((float)v, 1.0f);
        } else if (node == NN) {
            row_off[NN] = gbase + excl;   // == EE
        }
    }
    __syncthreads();

    int* cp = csr + gbase;
#pragma unroll
    for (int j = 0; j < 6; ++j) {
        if (dl[j] >= 0) cp[off[dl[j]] + lp[j]] = sv[j];
    }
}

// ---------------- x -> bf16 + fp8 shadows ----------------

__global__ __launch_bounds__(256) void k_x2bf(const float* __restrict__ x,
                                              u16* __restrict__ xb,
                                              u8* __restrict__ x8) {
    int i = (blockIdx.x * 256 + threadIdx.x) * 4;
    if (i < NN * DD) {
        float4 v = *(const float4*)(x + i);
        uint2 p;
        p.x = (u32)f2bf(v.x) | ((u32)f2bf(v.y) << 16);
        p.y = (u32)f2bf(v.z) | ((u32)f2bf(v.w) << 16);
        *(uint2*)(xb + i) = p;
        u32 r8 = __builtin_amdgcn_cvt_pk_fp8_f32(v.x, v.y, 0, false);
        r8 = __builtin_amdgcn_cvt_pk_fp8_f32(v.z, v.w, r8, true);
        *(u32*)(x8 + i) = r8;
    }
}

// ---------------- weight pack: [Ws;Wn] (256x128) -> MFMA B-fragment order, bf16 ----------------

__global__ __launch_bounds__(256) void k_wpack(const float* __restrict__ Ws,
                                               const float* __restrict__ Wn,
                                               u16* __restrict__ wpk) {
    int tid = blockIdx.x * 256 + threadIdx.x;   // 3 layers * 4096 frags
    if (tid >= 3 * 4096) return;
    int layer = tid >> 12;
    int rem = tid & 4095;
    int ks = rem >> 9;
    int nt = (rem >> 6) & 7;
    int lane = rem & 63;
    int n = nt * 16 + (lane & 15);
    int kb = ks * 32 + (lane >> 4) * 8;
    u16 o[8];
#pragma unroll
    for (int j = 0; j < 8; ++j) {
        int k = kb + j;
        float w = (k < DD) ? Ws[layer * DD * DD + k * DD + n]
                           : Wn[layer * DD * DD + (k - DD) * DD + n];
        o[j] = f2bf(w);
    }
    uint4 pk;
    pk.x = (u32)o[0] | ((u32)o[1] << 16);
    pk.y = (u32)o[2] | ((u32)o[3] << 16);
    pk.z = (u32)o[4] | ((u32)o[5] << 16);
    pk.w = (u32)o[6] | ((u32)o[7] << 16);
    *(uint4*)(wpk + (size_t)tid * 8) = pk;
}

// ---------------- fused SAGEConv layer: gather-mean + MFMA GEMM + epilogue ----------------
// block = 256 thr = 4 waves, 64 nodes. A = [h_bf16 | agg_bf16] (K=256) in LDS.
// h-half staged from hb (bf16); agg-half gathered from the FP8 shadow.
// NEW: the block's contiguous csr slice (<=EMAX edges) is staged to LDS first,
// removing the ~200cy L2 address-fetch from the gather dependency chain; the
// edge loop is 8-deep unrolled (8 independent gathers in flight).
// VGPR must stay <= 64: crossing it halves wave slots (R8: -35%).

__device__ __forceinline__ void acc8f8(float* a, uint2 u) {
    f32x2 f;
    f = __builtin_amdgcn_cvt_pk_f32_fp8((int)u.x, false); a[0] += f[0]; a[1] += f[1];
    f = __builtin_amdgcn_cvt_pk_f32_fp8((int)u.x, true);  a[2] += f[0]; a[3] += f[1];
    f = __builtin_amdgcn_cvt_pk_f32_fp8((int)u.y, false); a[4] += f[0]; a[5] += f[1];
    f = __builtin_amdgcn_cvt_pk_f32_fp8((int)u.y, true);  a[6] += f[0]; a[7] += f[1];
}

__global__ __launch_bounds__(256) void k_layer(const u16* __restrict__ hb,
                                               const u8* __restrict__ g8,
                                               const int* __restrict__ row_off,
                                               const int* __restrict__ csr,
                                               const float* __restrict__ inv_deg,
                                               const u16* __restrict__ wpk,
                                               const float* __restrict__ bias,
                                               const float* __restrict__ gmm,
                                               const float* __restrict__ bet,
                                               float* __restrict__ h_out,
                                               u16* __restrict__ hb_out,
                                               u8* __restrict__ g8_out,
                                               int do_ln) {
    __shared__ u16 A[64 * LDA];   // 33792 B
    __shared__ int E[EMAX];       // 8192 B edge cache
    int t = threadIdx.x;
    int b0 = blockIdx.x * 64;

    // stage h half (cols 0-127): 1024 chunks of 16B
#pragma unroll
    for (int j = 0; j < 4; ++j) {
        int idx = t + 256 * j;
        int r = idx >> 4;
        int c = idx & 15;
        int node = b0 + r;
        uint4 v = make_uint4(0, 0, 0, 0);
        if (node < NN) v = *(const uint4*)(hb + (size_t)node * DD + c * 8);
        *(uint4*)&A[r * LDA + c * 8] = v;
    }

    // stage this block's csr slice (contiguous for 64 consecutive nodes)
    int ebase = row_off[b0];
    int etop = row_off[(b0 + 64 < NN) ? (b0 + 64) : NN];
    int ecount = etop - ebase;
    bool lds_ok = (ecount <= EMAX);
    if (lds_ok) {
        for (int i = t; i < ecount; i += 256) E[i] = csr[ebase + i];
    }
    __syncthreads();   // E ready (A h-half writes also done; nobody reads A yet)

    // gather-mean agg half (cols 128-255): quad -> rows quad*4 .. quad*4+3
    int quad = t >> 4;          // 0..15
    int l16 = t & 15;
#pragma unroll
    for (int nn = 0; nn < 4; ++nn) {
        int r = quad * 4 + nn;
        int node = b0 + r;
        uint4 p = make_uint4(0, 0, 0, 0);
        if (node < NN) {
            float a[8] = {0.f, 0.f, 0.f, 0.f, 0.f, 0.f, 0.f, 0.f};
            int beg = row_off[node], end = row_off[node + 1];
            int e = beg;
            if (lds_ok) {
                for (; e + 8 <= end; e += 8) {
                    int ei = e - ebase;
                    int s0 = E[ei + 0], s1 = E[ei + 1], s2 = E[ei + 2], s3 = E[ei + 3];
                    int s4 = E[ei + 4], s5 = E[ei + 5], s6 = E[ei + 6], s7 = E[ei + 7];
                    uint2 u0 = *(const uint2*)(g8 + (size_t)s0 * DD + l16 * 8);
                    uint2 u1 = *(const uint2*)(g8 + (size_t)s1 * DD + l16 * 8);
                    uint2 u2 = *(const uint2*)(g8 + (size_t)s2 * DD + l16 * 8);
                    uint2 u3 = *(const uint2*)(g8 + (size_t)s3 * DD + l16 * 8);
                    uint2 u4 = *(const uint2*)(g8 + (size_t)s4 * DD + l16 * 8);
                    uint2 u5 = *(const uint2*)(g8 + (size_t)s5 * DD + l16 * 8);
                    uint2 u6 = *(const uint2*)(g8 + (size_t)s6 * DD + l16 * 8);
                    uint2 u7 = *(const uint2*)(g8 + (size_t)s7 * DD + l16 * 8);
                    acc8f8(a, u0); acc8f8(a, u1); acc8f8(a, u2); acc8f8(a, u3);
                    acc8f8(a, u4); acc8f8(a, u5); acc8f8(a, u6); acc8f8(a, u7);
                }
                for (; e + 4 <= end; e += 4) {
                    int ei = e - ebase;
                    int s0 = E[ei + 0], s1 = E[ei + 1], s2 = E[ei + 2], s3 = E[ei + 3];
                    uint2 u0 = *(const uint2*)(g8 + (size_t)s0 * DD + l16 * 8);
                    uint2 u1 = *(const uint2*)(g8 + (size_t)s1 * DD + l16 * 8);
                    uint2 u2 = *(const uint2*)(g8 + (size_t)s2 * DD + l16 * 8);
                    uint2 u3 = *(const uint2*)(g8 + (size_t)s3 * DD + l16 * 8);
                    acc8f8(a, u0); acc8f8(a, u1); acc8f8(a, u2); acc8f8(a, u3);
                }
                for (; e < end; ++e) {
                    int s0 = E[e - ebase];
                    uint2 u0 = *(const uint2*)(g8 + (size_t)s0 * DD + l16 * 8);
                    acc8f8(a, u0);
                }
            } else {
                // statistically-unreachable fallback, kept for correctness
                for (; e < end; ++e) {
                    int s0 = csr[e];
                    uint2 u0 = *(const uint2*)(g8 + (size_t)s0 * DD + l16 * 8);
                    acc8f8(a, u0);
                }
            }
            float sc = inv_deg[node];
            p.x = (u32)f2bf(a[0] * sc) | ((u32)f2bf(a[1] * sc) << 16);
            p.y = (u32)f2bf(a[2] * sc) | ((u32)f2bf(a[3] * sc) << 16);
            p.z = (u32)f2bf(a[4] * sc) | ((u32)f2bf(a[5] * sc) << 16);
            p.w = (u32)f2bf(a[6] * sc) | ((u32)f2bf(a[7] * sc) << 16);
        }
        *(uint4*)&A[r * LDA + 128 + l16 * 8] = p;
    }
    __syncthreads();

    int wv = t >> 6, lane = t & 63;
    int m = lane & 15, q = lane >> 4;

    f32x4 acc[8];
#pragma unroll
    for (int nt = 0; nt < 8; ++nt) acc[nt] = (f32x4)(0.f);

    const u16* Arow = &A[(wv * 16 + m) * LDA + q * 8];
    const short8* wp = (const short8*)wpk;
#pragma unroll
    for (int ks = 0; ks < 8; ++ks) {
        short8 af = *(const short8*)(Arow + ks * 32);
        const short8* bp = wp + (ks * 8) * 64 + lane;
#pragma unroll
        for (int nt = 0; nt < 8; ++nt) {
            short8 bf = bp[nt * 64];
            acc[nt] = __builtin_amdgcn_mfma_f32_16x16x32_bf16(af, bf, acc[nt], 0, 0, 0);
        }
    }

    // per-lane column constants
    float bcol[8], gcol[8], ecol[8];
#pragma unroll
    for (int nt = 0; nt < 8; ++nt) {
        bcol[nt] = bias[nt * 16 + m];
        if (do_ln) { gcol[nt] = gmm[nt * 16 + m]; ecol[nt] = bet[nt * 16 + m]; }
    }

    // epilogue per C-row j: node = b0 + wv*16 + q*4 + j
#pragma unroll
    for (int j = 0; j < 4; ++j) {
        int row = wv * 16 + q * 4 + j;
        int node = b0 + row;
        bool ok = node < NN;
        const u16* ar = &A[row * LDA];   // bf16 residual source (staged h row)
        float v[8];
        float s = 0.f, qq = 0.f;
#pragma unroll
        for (int nt = 0; nt < 8; ++nt) {
            float x = acc[nt][j] + bcol[nt] + bf2f(ar[nt * 16 + m]);  // bf16 residual
            if (do_ln) {
                x = fmaxf(x, 0.f);
                s += x; qq += x * x;
            }
            v[nt] = x;
        }
        if (do_ln) {
#pragma unroll
            for (int o = 1; o < 16; o <<= 1) {   // reduce across the quad's 16 lanes
                s += __shfl_xor(s, o);
                qq += __shfl_xor(qq, o);
            }
            float mu = s * (1.0f / 128.0f);
            float var = fmaxf(qq * (1.0f / 128.0f) - mu * mu, 0.f);
            float rs = rsqrtf(var + 1e-5f);
#pragma unroll
            for (int nt = 0; nt < 8; ++nt)
                v[nt] = gcol[nt] * (v[nt] - mu) * rs + ecol[nt];
        }
        if (ok) {
            if (h_out) {
                float* orow = h_out + (size_t)node * DD;
#pragma unroll
                for (int nt = 0; nt < 8; ++nt) orow[nt * 16 + m] = v[nt];
            }
            if (hb_out) {
                u16* brow = hb_out + (size_t)node * DD;
#pragma unroll
                for (int nt = 0; nt < 8; ++nt) brow[nt * 16 + m] = f2bf(v[nt]);
            }
            if (g8_out) {
                u8* brow8 = g8_out + (size_t)node * DD;
#pragma unroll
                for (int nt = 0; nt < 8; ++nt) {
                    u32 pk = __builtin_amdgcn_cvt_pk_fp8_f32(v[nt], v[nt], 0, false);
                    brow8[nt * 16 + m] = (u8)(pk & 0xffu);
                }
            }
        }
    }
}

// ---------------- output head: logits = h @ Wout + bout (fp32 vector) ----------------

__device__ __forceinline__ void stage_tile(const float* __restrict__ g, int b0,
                                           float* __restrict__ tile, int t) {
#pragma unroll
    for (int j = 0; j < 8; ++j) {
        int idx = t + 256 * j;
        int r = idx >> 5;
        int c = idx & 31;
        int node = b0 + r;
        float4 f = make_float4(0.f, 0.f, 0.f, 0.f);
        if (node < NN) f = *(const float4*)(g + (size_t)node * DD + c * 4);
        *(float4*)&tile[r * DD + c * 4] = f;
    }
}

__global__ __launch_bounds__(256) void k_logits(const float* __restrict__ h,
                                                const float* __restrict__ Wo,
                                                const float* __restrict__ bo,
                                                float* __restrict__ out) {
    __shared__ float tile[64 * DD];
    int t = threadIdx.x;
    int b0 = blockIdx.x * 64;
    int cg = t & 15;
    int ng = t >> 4;
    stage_tile(h, b0, tile, t);
    __syncthreads();
    float acc[4][4];
#pragma unroll
    for (int i = 0; i < 4; ++i)
#pragma unroll
        for (int j = 0; j < 4; ++j) acc[i][j] = 0.f;
    for (int k = 0; k < DD; k += 4) {
        float4 w0 = *(const float4*)(Wo + (k + 0) * CC + cg * 4);
        float4 w1 = *(const float4*)(Wo + (k + 1) * CC + cg * 4);
        float4 w2 = *(const float4*)(Wo + (k + 2) * CC + cg * 4);
        float4 w3 = *(const float4*)(Wo + (k + 3) * CC + cg * 4);
#pragma unroll
        for (int i = 0; i < 4; ++i) {
            float4 hv = *(const float4*)&tile[(ng * 4 + i) * DD + k];
            acc[i][0] = fmaf(hv.x, w0.x, fmaf(hv.y, w1.x, fmaf(hv.z, w2.x, fmaf(hv.w, w3.x, acc[i][0]))));
            acc[i][1] = fmaf(hv.x, w0.y, fmaf(hv.y, w1.y, fmaf(hv.z, w2.y, fmaf(hv.w, w3.y, acc[i][1]))));
            acc[i][2] = fmaf(hv.x, w0.z, fmaf(hv.y, w1.z, fmaf(hv.z, w2.z, fmaf(hv.w, w3.z, acc[i][2]))));
            acc[i][3] = fmaf(hv.x, w0.w, fmaf(hv.y, w1.w, fmaf(hv.z, w2.w, fmaf(hv.w, w3.w, acc[i][3]))));
        }
    }
    float4 b4 = *(const float4*)(bo + cg * 4);
#pragma unroll
    for (int i = 0; i < 4; ++i) {
        int node = b0 + ng * 4 + i;
        if (node < NN) {
            *(float4*)(out + (size_t)node * CC + cg * 4) =
                make_float4(acc[i][0] + b4.x, acc[i][1] + b4.y,
                            acc[i][2] + b4.z, acc[i][3] + b4.w);
        }
    }
}

// ---------------- launch ----------------

extern "C" void kernel_launch(void* const* d_in, const int* in_sizes, int n_in,
                              void* d_out, int out_size, void* d_ws, size_t ws_size,
                              hipStream_t stream) {
    const float* x  = (const float*)d_in[0];
    const int* src  = (const int*)d_in[1];
    const int* dst  = (const int*)d_in[2];
    const float* Ws = (const float*)d_in[3];
    const float* Wn = (const float*)d_in[4];
    const float* bc = (const float*)d_in[5];
    const float* gm = (const float*)d_in[6];
    const float* bt = (const float*)d_in[7];
    const float* Wo = (const float*)d_in[8];
    const float* bo = (const float*)d_in[9];
    float* out = (float*)d_out;   // fp32: logits [NN*CC] then embedding [NN*DD]
    float* emb = out + (size_t)NN * CC;

    char* p = (char*)d_ws;
    auto alloc = [&](size_t bytes) { void* r = (void*)p; p += (bytes + 255) & ~(size_t)255; return r; };
    u16* xb      = (u16*)alloc((size_t)NN * DD * 2);
    u16* hb0     = (u16*)alloc((size_t)NN * DD * 2);
    u16* hb1     = (u16*)alloc((size_t)NN * DD * 2);
    u8* x8       = (u8*)alloc((size_t)NN * DD);
    u8* h8_0     = (u8*)alloc((size_t)NN * DD);
    u8* h8_1     = (u8*)alloc((size_t)NN * DD);
    u16* wpk     = (u16*)alloc((size_t)3 * 4096 * 8 * 2);
    float* invd  = (float*)alloc(NN * 4);
    int* row_off = (int*)alloc((NN + 1) * 4);
    int* bcnt    = (int*)alloc(NBKT * 4);
    int* csr     = (int*)alloc(EE * 4);
    u32* bkt     = (u32*)alloc((size_t)NBKT * BCAP * 4);   // 4.8 MB

    hipMemsetAsync(bcnt, 0, NBKT * 4, stream);

    k_bucket<<<(EE + EPB - 1) / EPB, 1024, 0, stream>>>(src, dst, bcnt, bkt);
    k_fill2<<<NBKT, 512, 0, stream>>>(bcnt, bkt, row_off, invd, csr);
    k_x2bf<<<(NN * DD / 4 + 255) / 256, 256, 0, stream>>>(x, xb, x8);
    k_wpack<<<(3 * 4096 + 255) / 256, 256, 0, stream>>>(Ws, Wn, wpk);

    const int NB = (NN + 63) / 64;
    // layer 1: in xb/x8 -> hb0/h8_0
    k_layer<<<NB, 256, 0, stream>>>(xb, x8, row_off, csr, invd,
                                    wpk + (size_t)0 * 4096 * 8,
                                    bc + 0 * DD, gm + 0 * DD, bt + 0 * DD,
                                    (float*)nullptr, hb0, h8_0, 1);
    // layer 2: in hb0/h8_0 -> hb1/h8_1
    k_layer<<<NB, 256, 0, stream>>>(hb0, h8_0, row_off, csr, invd,
                                    wpk + (size_t)1 * 4096 * 8,
                                    bc + 1 * DD, gm + 1 * DD, bt + 1 * DD,
                                    (float*)nullptr, hb1, h8_1, 1);
    // layer 3: in hb1/h8_1 -> emb (fp32 into output), no LN, no shadows
    k_layer<<<NB, 256, 0, stream>>>(hb1, h8_1, row_off, csr, invd,
                                    wpk + (size_t)2 * 4096 * 8,
                                    bc + 2 * DD, (const float*)nullptr, (const float*)nullptr,
                                    emb, (u16*)nullptr, (u8*)nullptr, 0);
    k_logits<<<NB, 256, 0, stream>>>(emb, Wo, bo, out);
}

// Round 13
// 245.838 us; speedup vs baseline: 1.1682x; 1.1682x over previous
//
#include <hip/hip_runtime.h>

#define NN 50000
#define EE 800000
#define DD 128
#define CC 64
#define LDA 264    // LDS A row stride in u16: 256 data + 8 pad (2-way bank alias = free)
#define EMAX 2048  // u16 LDS edge-cache cap per 64-node block (mean 1024, sd 32 -> 32 sigma)

// bucketed CSR fill
#define BSH 7                                 // 128 dst-nodes per bucket
#define NBKT ((NN + (1 << BSH) - 1) >> BSH)   // 391
#define BCAP 3072                             // mean 2048, sd ~45 -> 22-sigma margin
#define EPB 4096                              // edges per bucket-block (1024 thr x 4)

typedef unsigned char u8;
typedef unsigned short u16;
typedef unsigned int u32;
typedef __attribute__((ext_vector_type(8))) short short8;   // 8 bf16
typedef __attribute__((ext_vector_type(4))) float f32x4;
typedef __attribute__((ext_vector_type(2))) float f32x2;

__device__ __forceinline__ float bf2f(u16 u) {
    union { u32 i; float f; } v; v.i = ((u32)u) << 16; return v.f;
}
__device__ __forceinline__ u16 f2bf(float f) {
    union { float f; u32 i; } v; v.f = f;
    u32 x = v.i;
    u32 r = x + 0x7fffu + ((x >> 16) & 1u);   // round-to-nearest-even
    return (u16)(r >> 16);
}

// ---------------- phase A: bucket edges by dst>>7, NO global per-edge atomics ----------------

__global__ __launch_bounds__(1024) void k_bucket(const int* __restrict__ src,
                                                 const int* __restrict__ dst,
                                                 int* __restrict__ bcnt,
                                                 u32* __restrict__ bkt) {
    __shared__ int cnt[NBKT];
    __shared__ int base[NBKT];
    int t = threadIdx.x;
    int e0 = blockIdx.x * EPB;
    for (int i = t; i < NBKT; i += 1024) cnt[i] = 0;
    __syncthreads();
    int bk[4], lp[4];
    u32 pk[4];
#pragma unroll
    for (int j = 0; j < 4; ++j) {
        int e = e0 + t + 1024 * j;
        if (e < EE) {
            int d = dst[e];
            int s = src[e];
            bk[j] = d >> BSH;
            pk[j] = (u32)s | ((u32)(d & 127) << 16);
            lp[j] = atomicAdd(&cnt[bk[j]], 1);
        } else {
            bk[j] = -1;
        }
    }
    __syncthreads();
    for (int i = t; i < NBKT; i += 1024)
        base[i] = atomicAdd(&bcnt[i], cnt[i]);
    __syncthreads();
#pragma unroll
    for (int j = 0; j < 4; ++j) {
        if (bk[j] >= 0)
            bkt[(size_t)bk[j] * BCAP + base[bk[j]] + lp[j]] = pk[j];
    }
}

// ---------------- phase B: one block per bucket: local histogram/scan -> row_off,
// inv_deg, csr (all contiguous single-block-owned writes) ----------------

__global__ __launch_bounds__(512) void k_fill2(const int* __restrict__ bcnt,
                                               const u32* __restrict__ bkt,
                                               int* __restrict__ row_off,
                                               float* __restrict__ inv_deg,
                                               int* __restrict__ csr) {
    __shared__ int cnt[128];
    __shared__ int off[128];
    __shared__ int wtot;
    int b = blockIdx.x;
    int t = threadIdx.x;
    int lane = t & 63;
    int n = bcnt[b];

    // exclusive prefix of bcnt[0..b) -- redundant per-wave reduce, L2-hot
    int part = 0;
    for (int i = lane; i < b; i += 64) part += bcnt[i];
#pragma unroll
    for (int o = 1; o < 64; o <<= 1) part += __shfl_xor(part, o);
    int gbase = part;   // same value in every wave

    if (t < 128) cnt[t] = 0;
    __syncthreads();

    const u32* bp = bkt + (size_t)b * BCAP;
    int dl[6], sv[6], lp[6];
#pragma unroll
    for (int j = 0; j < 6; ++j) {           // BCAP/512 = 6
        int i = t + 512 * j;
        if (i < n) {
            u32 pk = bp[i];
            dl[j] = (int)(pk >> 16) & 127;
            sv[j] = (int)(pk & 0xffffu);
            lp[j] = atomicAdd(&cnt[dl[j]], 1);
        } else {
            dl[j] = -1;
        }
    }
    __syncthreads();

    int x = 0, v = 0;
    if (t < 128) {
        v = cnt[t];
        x = v;
#pragma unroll
        for (int o = 1; o < 64; o <<= 1) {
            int y = __shfl_up(x, o, 64);
            if (lane >= o) x += y;
        }
        if (t == 63) wtot = x;
    }
    __syncthreads();
    if (t < 128) {
        int excl = x - v + ((t >= 64) ? wtot : 0);
        off[t] = excl;
        int node = (b << BSH) + t;
        if (node < NN) {
            row_off[node] = gbase + excl;
            inv_deg[node] = 1.0f / fmaxf((float)v, 1.0f);
        } else if (node == NN) {
            row_off[NN] = gbase + excl;   // == EE
        }
    }
    __syncthreads();

    int* cp = csr + gbase;
#pragma unroll
    for (int j = 0; j < 6; ++j) {
        if (dl[j] >= 0) cp[off[dl[j]] + lp[j]] = sv[j];
    }
}

// ---------------- x -> bf16 + fp8 shadows ----------------

__global__ __launch_bounds__(256) void k_x2bf(const float* __restrict__ x,
                                              u16* __restrict__ xb,
                                              u8* __restrict__ x8) {
    int i = (blockIdx.x * 256 + threadIdx.x) * 4;
    if (i < NN * DD) {
        float4 v = *(const float4*)(x + i);
        uint2 p;
        p.x = (u32)f2bf(v.x) | ((u32)f2bf(v.y) << 16);
        p.y = (u32)f2bf(v.z) | ((u32)f2bf(v.w) << 16);
        *(uint2*)(xb + i) = p;
        u32 r8 = __builtin_amdgcn_cvt_pk_fp8_f32(v.x, v.y, 0, false);
        r8 = __builtin_amdgcn_cvt_pk_fp8_f32(v.z, v.w, r8, true);
        *(u32*)(x8 + i) = r8;
    }
}

// ---------------- weight pack: [Ws;Wn] (256x128) -> MFMA B-fragment order, bf16 ----------------

__global__ __launch_bounds__(256) void k_wpack(const float* __restrict__ Ws,
                                               const float* __restrict__ Wn,
                                               u16* __restrict__ wpk) {
    int tid = blockIdx.x * 256 + threadIdx.x;   // 3 layers * 4096 frags
    if (tid >= 3 * 4096) return;
    int layer = tid >> 12;
    int rem = tid & 4095;
    int ks = rem >> 9;
    int nt = (rem >> 6) & 7;
    int lane = rem & 63;
    int n = nt * 16 + (lane & 15);
    int kb = ks * 32 + (lane >> 4) * 8;
    u16 o[8];
#pragma unroll
    for (int j = 0; j < 8; ++j) {
        int k = kb + j;
        float w = (k < DD) ? Ws[layer * DD * DD + k * DD + n]
                           : Wn[layer * DD * DD + (k - DD) * DD + n];
        o[j] = f2bf(w);
    }
    uint4 pk;
    pk.x = (u32)o[0] | ((u32)o[1] << 16);
    pk.y = (u32)o[2] | ((u32)o[3] << 16);
    pk.z = (u32)o[4] | ((u32)o[5] << 16);
    pk.w = (u32)o[6] | ((u32)o[7] << 16);
    *(uint4*)(wpk + (size_t)tid * 8) = pk;
}

// ---------------- fused SAGEConv layer: gather-mean + MFMA GEMM + epilogue ----------------
// block = 256 thr = 4 waves, 64 nodes. A = [h_bf16 | agg_bf16] (K=256) in LDS.
// h-half staged from hb (bf16); agg-half gathered from the FP8 shadow.
// The block's contiguous csr slice is staged to LDS as u16 (node ids < 65536):
// removes the ~200cy L2 address-fetch from the gather chain at only 4KB LDS
// (total 37.9KB keeps 4 blocks/CU -- R12's 42KB dropped to 3 and regressed).
// Edge loop stays 4-deep (R11-proven): VGPR must stay <= 64 (R8: cliff = -35%).

__device__ __forceinline__ void acc8f8(float* a, uint2 u) {
    f32x2 f;
    f = __builtin_amdgcn_cvt_pk_f32_fp8((int)u.x, false); a[0] += f[0]; a[1] += f[1];
    f = __builtin_amdgcn_cvt_pk_f32_fp8((int)u.x, true);  a[2] += f[0]; a[3] += f[1];
    f = __builtin_amdgcn_cvt_pk_f32_fp8((int)u.y, false); a[4] += f[0]; a[5] += f[1];
    f = __builtin_amdgcn_cvt_pk_f32_fp8((int)u.y, true);  a[6] += f[0]; a[7] += f[1];
}

__global__ __launch_bounds__(256) void k_layer(const u16* __restrict__ hb,
                                               const u8* __restrict__ g8,
                                               const int* __restrict__ row_off,
                                               const int* __restrict__ csr,
                                               const float* __restrict__ inv_deg,
                                               const u16* __restrict__ wpk,
                                               const float* __restrict__ bias,
                                               const float* __restrict__ gmm,
                                               const float* __restrict__ bet,
                                               float* __restrict__ h_out,
                                               u16* __restrict__ hb_out,
                                               u8* __restrict__ g8_out,
                                               int do_ln) {
    __shared__ u16 A[64 * LDA];   // 33792 B
    __shared__ u16 E[EMAX];       // 4096 B edge cache (u16 node ids)
    int t = threadIdx.x;
    int b0 = blockIdx.x * 64;

    // stage h half (cols 0-127): 1024 chunks of 16B
#pragma unroll
    for (int j = 0; j < 4; ++j) {
        int idx = t + 256 * j;
        int r = idx >> 4;
        int c = idx & 15;
        int node = b0 + r;
        uint4 v = make_uint4(0, 0, 0, 0);
        if (node < NN) v = *(const uint4*)(hb + (size_t)node * DD + c * 8);
        *(uint4*)&A[r * LDA + c * 8] = v;
    }

    // stage this block's csr slice (contiguous for 64 consecutive nodes)
    int ebase = row_off[b0];
    int etop = row_off[(b0 + 64 < NN) ? (b0 + 64) : NN];
    int ecount = etop - ebase;
    bool lds_ok = (ecount <= EMAX);
    if (lds_ok) {
        for (int i = t; i < ecount; i += 256) E[i] = (u16)csr[ebase + i];
    }
    __syncthreads();   // E ready (A h-half writes also done; nobody reads A yet)

    // gather-mean agg half (cols 128-255): quad -> rows quad*4 .. quad*4+3
    int quad = t >> 4;          // 0..15
    int l16 = t & 15;
#pragma unroll
    for (int nn = 0; nn < 4; ++nn) {
        int r = quad * 4 + nn;
        int node = b0 + r;
        uint4 p = make_uint4(0, 0, 0, 0);
        if (node < NN) {
            float a[8] = {0.f, 0.f, 0.f, 0.f, 0.f, 0.f, 0.f, 0.f};
            int beg = row_off[node], end = row_off[node + 1];
            int e = beg;
            if (lds_ok) {
                for (; e + 4 <= end; e += 4) {
                    int ei = e - ebase;
                    int s0 = E[ei + 0], s1 = E[ei + 1], s2 = E[ei + 2], s3 = E[ei + 3];
                    uint2 u0 = *(const uint2*)(g8 + (size_t)s0 * DD + l16 * 8);
                    uint2 u1 = *(const uint2*)(g8 + (size_t)s1 * DD + l16 * 8);
                    uint2 u2 = *(const uint2*)(g8 + (size_t)s2 * DD + l16 * 8);
                    uint2 u3 = *(const uint2*)(g8 + (size_t)s3 * DD + l16 * 8);
                    acc8f8(a, u0); acc8f8(a, u1); acc8f8(a, u2); acc8f8(a, u3);
                }
                for (; e < end; ++e) {
                    int s0 = E[e - ebase];
                    uint2 u0 = *(const uint2*)(g8 + (size_t)s0 * DD + l16 * 8);
                    acc8f8(a, u0);
                }
            } else {
                // statistically-unreachable fallback, kept for correctness
                for (; e < end; ++e) {
                    int s0 = csr[e];
                    uint2 u0 = *(const uint2*)(g8 + (size_t)s0 * DD + l16 * 8);
                    acc8f8(a, u0);
                }
            }
            float sc = inv_deg[node];
            p.x = (u32)f2bf(a[0] * sc) | ((u32)f2bf(a[1] * sc) << 16);
            p.y = (u32)f2bf(a[2] * sc) | ((u32)f2bf(a[3] * sc) << 16);
            p.z = (u32)f2bf(a[4] * sc) | ((u32)f2bf(a[5] * sc) << 16);
            p.w = (u32)f2bf(a[6] * sc) | ((u32)f2bf(a[7] * sc) << 16);
        }
        *(uint4*)&A[r * LDA + 128 + l16 * 8] = p;
    }
    __syncthreads();

    int wv = t >> 6, lane = t & 63;
    int m = lane & 15, q = lane >> 4;

    f32x4 acc[8];
#pragma unroll
    for (int nt = 0; nt < 8; ++nt) acc[nt] = (f32x4)(0.f);

    const u16* Arow = &A[(wv * 16 + m) * LDA + q * 8];
    const short8* wp = (const short8*)wpk;
#pragma unroll
    for (int ks = 0; ks < 8; ++ks) {
        short8 af = *(const short8*)(Arow + ks * 32);
        const short8* bp = wp + (ks * 8) * 64 + lane;
#pragma unroll
        for (int nt = 0; nt < 8; ++nt) {
            short8 bf = bp[nt * 64];
            acc[nt] = __builtin_amdgcn_mfma_f32_16x16x32_bf16(af, bf, acc[nt], 0, 0, 0);
        }
    }

    // per-lane column constants
    float bcol[8], gcol[8], ecol[8];
#pragma unroll
    for (int nt = 0; nt < 8; ++nt) {
        bcol[nt] = bias[nt * 16 + m];
        if (do_ln) { gcol[nt] = gmm[nt * 16 + m]; ecol[nt] = bet[nt * 16 + m]; }
    }

    // epilogue per C-row j: node = b0 + wv*16 + q*4 + j
#pragma unroll
    for (int j = 0; j < 4; ++j) {
        int row = wv * 16 + q * 4 + j;
        int node = b0 + row;
        bool ok = node < NN;
        const u16* ar = &A[row * LDA];   // bf16 residual source (staged h row)
        float v[8];
        float s = 0.f, qq = 0.f;
#pragma unroll
        for (int nt = 0; nt < 8; ++nt) {
            float x = acc[nt][j] + bcol[nt] + bf2f(ar[nt * 16 + m]);  // bf16 residual
            if (do_ln) {
                x = fmaxf(x, 0.f);
                s += x; qq += x * x;
            }
            v[nt] = x;
        }
        if (do_ln) {
#pragma unroll
            for (int o = 1; o < 16; o <<= 1) {   // reduce across the quad's 16 lanes
                s += __shfl_xor(s, o);
                qq += __shfl_xor(qq, o);
            }
            float mu = s * (1.0f / 128.0f);
            float var = fmaxf(qq * (1.0f / 128.0f) - mu * mu, 0.f);
            float rs = rsqrtf(var + 1e-5f);
#pragma unroll
            for (int nt = 0; nt < 8; ++nt)
                v[nt] = gcol[nt] * (v[nt] - mu) * rs + ecol[nt];
        }
        if (ok) {
            if (h_out) {
                float* orow = h_out + (size_t)node * DD;
#pragma unroll
                for (int nt = 0; nt < 8; ++nt) orow[nt * 16 + m] = v[nt];
            }
            if (hb_out) {
                u16* brow = hb_out + (size_t)node * DD;
#pragma unroll
                for (int nt = 0; nt < 8; ++nt) brow[nt * 16 + m] = f2bf(v[nt]);
            }
            if (g8_out) {
                u8* brow8 = g8_out + (size_t)node * DD;
#pragma unroll
                for (int nt = 0; nt < 8; ++nt) {
                    u32 pk = __builtin_amdgcn_cvt_pk_fp8_f32(v[nt], v[nt], 0, false);
                    brow8[nt * 16 + m] = (u8)(pk & 0xffu);
                }
            }
        }
    }
}

// ---------------- output head: logits = h @ Wout + bout (fp32 vector) ----------------

__device__ __forceinline__ void stage_tile(const float* __restrict__ g, int b0,
                                           float* __restrict__ tile, int t) {
#pragma unroll
    for (int j = 0; j < 8; ++j) {
        int idx = t + 256 * j;
        int r = idx >> 5;
        int c = idx & 31;
        int node = b0 + r;
        float4 f = make_float4(0.f, 0.f, 0.f, 0.f);
        if (node < NN) f = *(const float4*)(g + (size_t)node * DD + c * 4);
        *(float4*)&tile[r * DD + c * 4] = f;
    }
}

__global__ __launch_bounds__(256) void k_logits(const float* __restrict__ h,
                                                const float* __restrict__ Wo,
                                                const float* __restrict__ bo,
                                                float* __restrict__ out) {
    __shared__ float tile[64 * DD];
    int t = threadIdx.x;
    int b0 = blockIdx.x * 64;
    int cg = t & 15;
    int ng = t >> 4;
    stage_tile(h, b0, tile, t);
    __syncthreads();
    float acc[4][4];
#pragma unroll
    for (int i = 0; i < 4; ++i)
#pragma unroll
        for (int j = 0; j < 4; ++j) acc[i][j] = 0.f;
    for (int k = 0; k < DD; k += 4) {
        float4 w0 = *(const float4*)(Wo + (k + 0) * CC + cg * 4);
        float4 w1 = *(const float4*)(Wo + (k + 1) * CC + cg * 4);
        float4 w2 = *(const float4*)(Wo + (k + 2) * CC + cg * 4);
        float4 w3 = *(const float4*)(Wo + (k + 3) * CC + cg * 4);
#pragma unroll
        for (int i = 0; i < 4; ++i) {
            float4 hv = *(const float4*)&tile[(ng * 4 + i) * DD + k];
            acc[i][0] = fmaf(hv.x, w0.x, fmaf(hv.y, w1.x, fmaf(hv.z, w2.x, fmaf(hv.w, w3.x, acc[i][0]))));
            acc[i][1] = fmaf(hv.x, w0.y, fmaf(hv.y, w1.y, fmaf(hv.z, w2.y, fmaf(hv.w, w3.y, acc[i][1]))));
            acc[i][2] = fmaf(hv.x, w0.z, fmaf(hv.y, w1.z, fmaf(hv.z, w2.z, fmaf(hv.w, w3.z, acc[i][2]))));
            acc[i][3] = fmaf(hv.x, w0.w, fmaf(hv.y, w1.w, fmaf(hv.z, w2.w, fmaf(hv.w, w3.w, acc[i][3]))));
        }
    }
    float4 b4 = *(const float4*)(bo + cg * 4);
#pragma unroll
    for (int i = 0; i < 4; ++i) {
        int node = b0 + ng * 4 + i;
        if (node < NN) {
            *(float4*)(out + (size_t)node * CC + cg * 4) =
                make_float4(acc[i][0] + b4.x, acc[i][1] + b4.y,
                            acc[i][2] + b4.z, acc[i][3] + b4.w);
        }
    }
}

// ---------------- launch ----------------

extern "C" void kernel_launch(void* const* d_in, const int* in_sizes, int n_in,
                              void* d_out, int out_size, void* d_ws, size_t ws_size,
                              hipStream_t stream) {
    const float* x  = (const float*)d_in[0];
    const int* src  = (const int*)d_in[1];
    const int* dst  = (const int*)d_in[2];
    const float* Ws = (const float*)d_in[3];
    const float* Wn = (const float*)d_in[4];
    const float* bc = (const float*)d_in[5];
    const float* gm = (const float*)d_in[6];
    const float* bt = (const float*)d_in[7];
    const float* Wo = (const float*)d_in[8];
    const float* bo = (const float*)d_in[9];
    float* out = (float*)d_out;   // fp32: logits [NN*CC] then embedding [NN*DD]
    float* emb = out + (size_t)NN * CC;

    char* p = (char*)d_ws;
    auto alloc = [&](size_t bytes) { void* r = (void*)p; p += (bytes + 255) & ~(size_t)255; return r; };
    u16* xb      = (u16*)alloc((size_t)NN * DD * 2);
    u16* hb0     = (u16*)alloc((size_t)NN * DD * 2);
    u16* hb1     = (u16*)alloc((size_t)NN * DD * 2);
    u8* x8       = (u8*)alloc((size_t)NN * DD);
    u8* h8_0     = (u8*)alloc((size_t)NN * DD);
    u8* h8_1     = (u8*)alloc((size_t)NN * DD);
    u16* wpk     = (u16*)alloc((size_t)3 * 4096 * 8 * 2);
    float* invd  = (float*)alloc(NN * 4);
    int* row_off = (int*)alloc((NN + 1) * 4);
    int* bcnt    = (int*)alloc(NBKT * 4);
    int* csr     = (int*)alloc(EE * 4);
    u32* bkt     = (u32*)alloc((size_t)NBKT * BCAP * 4);   // 4.8 MB

    hipMemsetAsync(bcnt, 0, NBKT * 4, stream);

    k_bucket<<<(EE + EPB - 1) / EPB, 1024, 0, stream>>>(src, dst, bcnt, bkt);
    k_fill2<<<NBKT, 512, 0, stream>>>(bcnt, bkt, row_off, invd, csr);
    k_x2bf<<<(NN * DD / 4 + 255) / 256, 256, 0, stream>>>(x, xb, x8);
    k_wpack<<<(3 * 4096 + 255) / 256, 256, 0, stream>>>(Ws, Wn, wpk);

    const int NB = (NN + 63) / 64;
    // layer 1: in xb/x8 -> hb0/h8_0
    k_layer<<<NB, 256, 0, stream>>>(xb, x8, row_off, csr, invd,
                                    wpk + (size_t)0 * 4096 * 8,
                                    bc + 0 * DD, gm + 0 * DD, bt + 0 * DD,
                                    (float*)nullptr, hb0, h8_0, 1);
    // layer 2: in hb0/h8_0 -> hb1/h8_1
    k_layer<<<NB, 256, 0, stream>>>(hb0, h8_0, row_off, csr, invd,
                                    wpk + (size_t)1 * 4096 * 8,
                                    bc + 1 * DD, gm + 1 * DD, bt + 1 * DD,
                                    (float*)nullptr, hb1, h8_1, 1);
    // layer 3: in hb1/h8_1 -> emb (fp32 into output), no LN, no shadows
    k_layer<<<NB, 256, 0, stream>>>(hb1, h8_1, row_off, csr, invd,
                                    wpk + (size_t)2 * 4096 * 8,
                                    bc + 2 * DD, (const float*)nullptr, (const float*)nullptr,
                                    emb, (u16*)nullptr, (u8*)nullptr, 0);
    k_logits<<<NB, 256, 0, stream>>>(emb, Wo, bo, out);
}